// Round 6
// baseline (240.449 us; speedup 1.0000x reference)
//
#include <hip/hip_runtime.h>
#include <hip/hip_cooperative_groups.h>

namespace cg = cooperative_groups;

// Problem constants
#define NSEG   4480     // 70 * 64
#define ADIM   64
#define BDIM   16
#define NEDGE  65536
#define DPB    32       // destinations (output rows) per block
#define NBLK   (NSEG / DPB)   // 140 blocks -> 1 block/CU, co-resident (coop OK)
#define TPB    1024     // 16 waves
#define CAP    64       // bucket capacity per dst (Poisson mean 14.6, max ~35)
#define GSP    1096     // Gs pitch in bf16 elems: 1088 + 8 pad

// ONE cooperative dispatch. Evidence across R0-R5: poison fill is a fixed
// ~40 us; each extra dispatch costs ~8-10 us (R2's 5-dispatch chain vs R4's
// single); R4's in-kernel per-block scan of pair[] cost 52 us. So: keep the
// edge-parallel scatter (full-grid TLP) but replace the two kernel
// boundaries with grid.sync() inside one cooperative kernel.
//   phase 0: first 4480 threads zero cnt[];            grid.sync()
//   phase 1: threads 0..65535 scatter {e,src} into global buckets (one
//            device-scope atomicAdd on 17.9 KB L2-resident counters);
//            grid.sync()  (carries the release/acquire fence)
//   phase 2: wave w accums dsts {2w, 2w+1}: 2 streams x 2-edge unroll = 4
//            independent load chains; readlane-broadcast {e,src} -> uniform
//            scalar bond/atom addresses; branchless validity via sanitized
//            indices + 0/1 scale (poison-safe); exact f32 accum, single
//            bf16 rounding into LDS Gs.
//   phase 3: waves 0..7: out[32,64] = Gs[32,1088] @ K2[1088,64] via
//            mfma_16x16x32_bf16, software-pipelined B loads straight from
//            kern/bias (8 contiguous floats per lane -> registers).
// Cross-block data (cnt) is re-read after grid.sync with device-scope
// atomic loads (G16: per-XCD L2 non-coherence); eb lines were never
// read-cached locally before the sync.
// LDS: 32*1096*2 = 70,144 B. Workspace: eb @0 (2.29 MB), cnt @4 MiB.
#define CNT_OFF  (4u << 20)

typedef __bf16 bf16x8 __attribute__((ext_vector_type(8)));
typedef float  f32x4  __attribute__((ext_vector_type(4)));

__device__ __forceinline__ unsigned short f2bf(float f) {
    union { float f; unsigned int i; } c; c.f = f;
    unsigned int x = c.i;
    x += 0x7fffu + ((x >> 16) & 1u);   // round-to-nearest-even
    return (unsigned short)(x >> 16);
}

union U8 { unsigned short u[8]; bf16x8 v; };

__device__ __forceinline__ bf16x8 pack_bf8(float4 a, float4 b) {
    U8 r;
    r.u[0] = f2bf(a.x); r.u[1] = f2bf(a.y); r.u[2] = f2bf(a.z); r.u[3] = f2bf(a.w);
    r.u[4] = f2bf(b.x); r.u[5] = f2bf(b.y); r.u[6] = f2bf(b.z); r.u[7] = f2bf(b.w);
    return r.v;
}

// load 16 bond floats for edge e (wave-uniform address), scaled by sc
__device__ __forceinline__ void load_bond16(const float* __restrict__ bond,
                                            int e, float* bb) {
    const float4* bp = (const float4*)(bond + (size_t)e * BDIM);
    const float4 c0 = bp[0], c1 = bp[1], c2 = bp[2], c3 = bp[3];
    bb[0]=c0.x; bb[1]=c0.y; bb[2]=c0.z; bb[3]=c0.w;
    bb[4]=c1.x; bb[5]=c1.y; bb[6]=c1.z; bb[7]=c1.w;
    bb[8]=c2.x; bb[9]=c2.y; bb[10]=c2.z; bb[11]=c2.w;
    bb[12]=c3.x; bb[13]=c3.y; bb[14]=c3.z; bb[15]=c3.w;
}

__global__ __launch_bounds__(TPB) void fused_kernel(
    const float* __restrict__ atom,    // [4480, 64]  f32
    const float* __restrict__ bond,    // [65536, 16] f32
    const int*   __restrict__ pair,    // [65536, 2]  int32 {dst, src}
    const float* __restrict__ kern,    // [16, 4096]  f32
    const float* __restrict__ bias,    // [4096]      f32
    float*       __restrict__ out,     // [4480, 64]  f32
    int*         __restrict__ cnt,     // [4480]      ws
    int2*        __restrict__ eb)      // [4480, 64]  ws {edge, src}
{
    __shared__ unsigned short Gs[DPB * GSP];       // bf16 G tile (70 KB)

    cg::grid_group grid = cg::this_grid();

    const int t    = threadIdx.x;
    const int gtid = blockIdx.x * TPB + t;         // 0 .. 143359

    // ---- phase 0: zero counters ----------------------------------------
    if (gtid < NSEG) cnt[gtid] = 0;
    __threadfence();
    grid.sync();

    // ---- phase 1: edge-parallel scatter --------------------------------
    if (gtid < NEDGE) {
        const int2 p = ((const int2*)pair)[gtid];  // .x = dst, .y = src
        const int idx = atomicAdd(&cnt[p.x], 1);   // device-scope by default
        if (idx < CAP) eb[(size_t)p.x * CAP + idx] = make_int2(gtid, p.y);
    }
    __threadfence();
    grid.sync();

    const int lane = t & 63;
    const int w    = t >> 6;                       // wave 0..15
    const int dlo  = blockIdx.x * DPB;

    // ---- phase 2: per-dst outer-product accumulation into Gs -----------
    {
        const int da = dlo + 2 * w;
        const int db = da + 1;
        int na = __hip_atomic_load(&cnt[da], __ATOMIC_RELAXED,
                                   __HIP_MEMORY_SCOPE_AGENT);
        int nb = __hip_atomic_load(&cnt[db], __ATOMIC_RELAXED,
                                   __HIP_MEMORY_SCOPE_AGENT);
        na = na < CAP ? na : CAP;
        nb = nb < CAP ? nb : CAP;
        const int2 mya = eb[(size_t)da * CAP + lane];   // lane l = entry l
        const int2 myb = eb[(size_t)db * CAP + lane];

        float ga[17], gb[17];
#pragma unroll
        for (int r = 0; r < 17; ++r) { ga[r] = 0.f; gb[r] = 0.f; }

        const int nmax = na > nb ? na : nb;
        for (int k = 0; k < nmax; k += 2) {
            // four candidate edges; sanitize invalid ones to index 0 with
            // scale 0 (bucket slots beyond the count hold poison -> must
            // not be dereferenced raw)
            const bool va0 = k < na, va1 = k + 1 < na;
            const bool vb0 = k < nb, vb1 = k + 1 < nb;
            int ea0 = __builtin_amdgcn_readlane(mya.x, k);
            int sa0 = __builtin_amdgcn_readlane(mya.y, k);
            int ea1 = __builtin_amdgcn_readlane(mya.x, k + 1);
            int sa1 = __builtin_amdgcn_readlane(mya.y, k + 1);
            int eb0 = __builtin_amdgcn_readlane(myb.x, k);
            int sb0 = __builtin_amdgcn_readlane(myb.y, k);
            int eb1 = __builtin_amdgcn_readlane(myb.x, k + 1);
            int sb1 = __builtin_amdgcn_readlane(myb.y, k + 1);
            ea0 = va0 ? ea0 : 0;  sa0 = va0 ? sa0 : 0;
            ea1 = va1 ? ea1 : 0;  sa1 = va1 ? sa1 : 0;
            eb0 = vb0 ? eb0 : 0;  sb0 = vb0 ? sb0 : 0;
            eb1 = vb1 ? eb1 : 0;  sb1 = vb1 ? sb1 : 0;

            // issue all 8 loads (4 atom VMEM + 4 bond scalar) before FMAs
            const float aa0 = atom[(size_t)sa0 * ADIM + lane] * (va0 ? 1.f : 0.f);
            const float aa1 = atom[(size_t)sa1 * ADIM + lane] * (va1 ? 1.f : 0.f);
            const float ab0 = atom[(size_t)sb0 * ADIM + lane] * (vb0 ? 1.f : 0.f);
            const float ab1 = atom[(size_t)sb1 * ADIM + lane] * (vb1 ? 1.f : 0.f);
            float ba0[16], ba1[16], bb0[16], bb1[16];
            load_bond16(bond, ea0, ba0);
            load_bond16(bond, ea1, ba1);
            load_bond16(bond, eb0, bb0);
            load_bond16(bond, eb1, bb1);

#pragma unroll
            for (int r = 0; r < 16; ++r) {
                ga[r] = fmaf(aa0, ba0[r], ga[r]);
                ga[r] = fmaf(aa1, ba1[r], ga[r]);
                gb[r] = fmaf(ab0, bb0[r], gb[r]);
                gb[r] = fmaf(ab1, bb1[r], gb[r]);
            }
            ga[16] += aa0 + aa1;
            gb[16] += ab0 + ab1;
        }

        // lane j writes G[d, r*64+j]: 128 B contiguous per r (2 lanes/bank)
#pragma unroll
        for (int r = 0; r < 17; ++r) {
            Gs[(2 * w) * GSP + r * 64 + lane]     = f2bf(ga[r]);
            Gs[(2 * w + 1) * GSP + r * 64 + lane] = f2bf(gb[r]);
        }
    }
    __syncthreads();

    // ---- phase 3: out = Gs @ K2 (MFMA, B direct from global) -----------
    // Fragment layouts (m89/m91-verified, passed R2-R5): A: row=lane&15,
    // k=quad*8+j; B: col=lane&15, k=quad*8+j; D: col=lane&15, row=quad*4+reg.
    if (w < 8) {
        const int mt   = w >> 2;                   // M tile 0/1
        const int ct   = w & 3;                    // N tile 0..3
        const int m    = lane & 15;
        const int quad = lane >> 4;
        const int c    = ct * 16 + m;              // output col (B col n)
        const unsigned short* Ga = Gs + (size_t)(mt * 16 + m) * GSP;

        f32x4 acc = {0.f, 0.f, 0.f, 0.f};

        const float* ks0 = kern + (size_t)c * 64 + quad * 8;
        float4 x0 = *(const float4*)(ks0);
        float4 x1 = *(const float4*)(ks0 + 4);
        float4 y0 = *(const float4*)(ks0 + 32);
        float4 y1 = *(const float4*)(ks0 + 36);

#pragma unroll
        for (int r = 0; r < 17; ++r) {
            float4 nx0 = {}, nx1 = {}, ny0 = {}, ny1 = {};
            if (r + 1 < 17) {                      // prefetch next slice
                const float* ns = ((r + 1 < 16) ? (kern + (size_t)(r + 1) * 4096)
                                                : bias)
                                  + (size_t)c * 64 + quad * 8;
                nx0 = *(const float4*)(ns);
                nx1 = *(const float4*)(ns + 4);
                ny0 = *(const float4*)(ns + 32);
                ny1 = *(const float4*)(ns + 36);
            }
            const bf16x8 a0 = *(const bf16x8*)(Ga + r * 64 + quad * 8);
            const bf16x8 a1 = *(const bf16x8*)(Ga + r * 64 + 32 + quad * 8);
            acc = __builtin_amdgcn_mfma_f32_16x16x32_bf16(a0, pack_bf8(x0, x1), acc, 0, 0, 0);
            acc = __builtin_amdgcn_mfma_f32_16x16x32_bf16(a1, pack_bf8(y0, y1), acc, 0, 0, 0);
            x0 = nx0; x1 = nx1; y0 = ny0; y1 = ny1;
        }

        // D: row = dlo + mt*16 + quad*4 + rr, col = c. Every row written once.
#pragma unroll
        for (int rr = 0; rr < 4; ++rr)
            out[(size_t)(dlo + mt * 16 + quad * 4 + rr) * ADIM + c] = acc[rr];
    }
}

extern "C" void kernel_launch(void* const* d_in, const int* in_sizes, int n_in,
                              void* d_out, int out_size, void* d_ws, size_t ws_size,
                              hipStream_t stream) {
    const float* atom = (const float*)d_in[0];
    const float* bond = (const float*)d_in[1];
    const int*   pair = (const int*)  d_in[2];
    const float* kern = (const float*)d_in[3];
    const float* bias = (const float*)d_in[4];
    float* out = (float*)d_out;

    int2* eb  = (int2*)d_ws;                         // 2.29 MB buckets
    int*  cnt = (int*)((char*)d_ws + CNT_OFF);       // 17.9 KB counters

    void* args[] = { (void*)&atom, (void*)&bond, (void*)&pair, (void*)&kern,
                     (void*)&bias, (void*)&out,  (void*)&cnt,  (void*)&eb };
    hipLaunchCooperativeKernel(reinterpret_cast<void*>(fused_kernel),
                               dim3(NBLK), dim3(TPB), args, 0, stream);
}

// Round 7
// 112.292 us; speedup vs baseline: 2.1413x; 2.1413x over previous
//
#include <hip/hip_runtime.h>

// Problem constants
#define NSEG   4480     // 70 * 64
#define ADIM   64
#define BDIM   16
#define NEDGE  65536
#define DPB    16       // destinations (output rows) per fused block
#define NBLK   (NSEG / DPB)   // 280 blocks -> every CU busy (~1.1 blocks/CU)
#define TPB    512      // 8 waves: 2 dsts per wave (phase A), K-split GEMM (phase B)
#define CAP    64       // bucket capacity per dst (Poisson mean 14.6, max ~35)
#define GSP    1096     // Gs pitch in bf16 elems: 1088 + 8 pad

// 3 plain dispatches (R5 structure, proven 92.2; R6's cooperative variant
// regressed to 240: grid.sync/threadfence forced L2 writebacks of the
// poison-dirtied cache). Fixes vs R5's fused kernel:
//  - phase A: 2 dsts/wave x 2-edge unroll = 4 independent load chains
//    (R5 had 2; in-order waves pay full L2 latency per chain-step)
//  - phase B: all 8 waves via K-split x2 + LDS reduction (halves the
//    exposed per-slice L2 latency of the kern loads)
//  - 280 x 512 shape: 8.75 waves/CU, no idle CUs (R4/R6's 140-block
//    shapes left ~45% of CUs empty -> Occ 18%)
//
// Workspace: eb @ 0 : 4480*64*8 = 2,293,760 B {edge,src} buckets
//            cnt @ 4 MiB : 4480*4 B counters (memset each iteration)
#define CNT_OFF  (4u << 20)

typedef __bf16 bf16x8 __attribute__((ext_vector_type(8)));
typedef float  f32x4  __attribute__((ext_vector_type(4)));

__device__ __forceinline__ unsigned short f2bf(float f) {
    union { float f; unsigned int i; } c; c.f = f;
    unsigned int x = c.i;
    x += 0x7fffu + ((x >> 16) & 1u);   // round-to-nearest-even
    return (unsigned short)(x >> 16);
}

union U8 { unsigned short u[8]; bf16x8 v; };

__device__ __forceinline__ bf16x8 pack_bf8(float4 a, float4 b) {
    U8 r;
    r.u[0] = f2bf(a.x); r.u[1] = f2bf(a.y); r.u[2] = f2bf(a.z); r.u[3] = f2bf(a.w);
    r.u[4] = f2bf(b.x); r.u[5] = f2bf(b.y); r.u[6] = f2bf(b.z); r.u[7] = f2bf(b.w);
    return r.v;
}

__device__ __forceinline__ void load_bond16(const float* __restrict__ bond,
                                            int e, float* bb) {
    const float4* bp = (const float4*)(bond + (size_t)e * BDIM);
    const float4 c0 = bp[0], c1 = bp[1], c2 = bp[2], c3 = bp[3];
    bb[0]=c0.x;  bb[1]=c0.y;  bb[2]=c0.z;  bb[3]=c0.w;
    bb[4]=c1.x;  bb[5]=c1.y;  bb[6]=c1.z;  bb[7]=c1.w;
    bb[8]=c2.x;  bb[9]=c2.y;  bb[10]=c2.z; bb[11]=c2.w;
    bb[12]=c3.x; bb[13]=c3.y; bb[14]=c3.z; bb[15]=c3.w;
}

// ---------------------------------------------------------------------------
// scatter_kernel: edge-parallel bucketing (proven R5). One coalesced int2
// load, one atomicAdd on the 17.9 KB L2-resident counter array, one 8 B
// bucket store. 65536 threads -> latency hidden by TLP.
// ---------------------------------------------------------------------------
__global__ __launch_bounds__(256) void scatter_kernel(
    const int* __restrict__ pair, int* __restrict__ cnt, int2* __restrict__ eb)
{
    const int e  = blockIdx.x * 256 + threadIdx.x;
    const int2 p = ((const int2*)pair)[e];          // .x = dst, .y = src
    const int idx = atomicAdd(&cnt[p.x], 1);
    if (idx < CAP) eb[(size_t)p.x * CAP + idx] = make_int2(e, p.y);
}

// ---------------------------------------------------------------------------
// fused_kernel:
//   phase A (8 waves, 2 dsts each): g[r] = sum_e bond[e,r]*atom[src_e,:]
//     (r<16), g[16] = sum_e atom[src_e,:]. Bucket rows loaded ONCE (lane l
//     = entry l); readlane broadcasts {e,src} -> uniform scalar addresses;
//     2 dsts x 2-edge unroll = 4 independent load chains; branchless
//     validity via sanitized indices + 0/1 scale (poison-safe, R6-proven).
//     Exact f32 accum, single bf16 rounding into LDS Gs.
//   phase B (8 waves): out[16,64] = Gs[16,1088] @ K2[1088,64] via
//     mfma_16x16x32_bf16. Wave w -> col-tile ct=w&3, K-half kh=w>>2
//     (slices 0..8 / 9..16); software-pipelined B loads straight from
//     kern/bias (8 contiguous floats per lane); kh=1 partials reduced via
//     LDS. K2[r*64+j, c] = kern[r, c*64+j] (r<16) / bias[c*64+j] (r=16).
// Fragment layouts (m89/m91-verified, passed R2-R6): A: row=lane&15,
// k=quad*8+j; B: col=lane&15, k=quad*8+j; D: col=lane&15, row=quad*4+reg.
// LDS: 16*1096*2 + 4*64*16 = 39.2 KB.
// ---------------------------------------------------------------------------
__global__ __launch_bounds__(TPB) void fused_kernel(
    const float* __restrict__ atom,    // [4480, 64]  f32
    const float* __restrict__ bond,    // [65536, 16] f32
    const int*   __restrict__ cnt,     // [4480]
    const int2*  __restrict__ eb,      // [4480, 64] {edge, src}
    const float* __restrict__ kern,    // [16, 4096]  f32
    const float* __restrict__ bias,    // [4096]      f32
    float*       __restrict__ out)     // [4480, 64]  f32
{
    __shared__ unsigned short Gs[DPB * GSP];       // bf16 G tile (35 KB)
    __shared__ f32x4 pb[4][64];                    // K-split partials (4 KB)

    const int t    = threadIdx.x;
    const int lane = t & 63;
    const int w    = t >> 6;                       // wave 0..7
    const int dlo  = blockIdx.x * DPB;

    // ---- phase A: accumulate 2 dsts per wave ----------------------------
    {
        const int da = dlo + 2 * w;
        const int db = da + 1;
        int na = cnt[da]; na = na < CAP ? na : CAP;
        int nb = cnt[db]; nb = nb < CAP ? nb : CAP;
        const int2 mya = eb[(size_t)da * CAP + lane];   // lane l = entry l
        const int2 myb = eb[(size_t)db * CAP + lane];

        float ga[17], gb[17];
#pragma unroll
        for (int r = 0; r < 17; ++r) { ga[r] = 0.f; gb[r] = 0.f; }

        const int nmax = na > nb ? na : nb;
        for (int k = 0; k < nmax; k += 2) {
            // sanitize: slots >= count hold poison, never dereference raw
            const bool va0 = k < na, va1 = k + 1 < na;
            const bool vb0 = k < nb, vb1 = k + 1 < nb;
            int ea0 = __builtin_amdgcn_readlane(mya.x, k);
            int sa0 = __builtin_amdgcn_readlane(mya.y, k);
            int ea1 = __builtin_amdgcn_readlane(mya.x, k + 1);
            int sa1 = __builtin_amdgcn_readlane(mya.y, k + 1);
            int eb0 = __builtin_amdgcn_readlane(myb.x, k);
            int sb0 = __builtin_amdgcn_readlane(myb.y, k);
            int eb1 = __builtin_amdgcn_readlane(myb.x, k + 1);
            int sb1 = __builtin_amdgcn_readlane(myb.y, k + 1);
            ea0 = va0 ? ea0 : 0;  sa0 = va0 ? sa0 : 0;
            ea1 = va1 ? ea1 : 0;  sa1 = va1 ? sa1 : 0;
            eb0 = vb0 ? eb0 : 0;  sb0 = vb0 ? sb0 : 0;
            eb1 = vb1 ? eb1 : 0;  sb1 = vb1 ? sb1 : 0;

            // issue all 8 loads (4 chains) before any FMA
            const float aa0 = atom[(size_t)sa0 * ADIM + lane] * (va0 ? 1.f : 0.f);
            const float aa1 = atom[(size_t)sa1 * ADIM + lane] * (va1 ? 1.f : 0.f);
            const float ab0 = atom[(size_t)sb0 * ADIM + lane] * (vb0 ? 1.f : 0.f);
            const float ab1 = atom[(size_t)sb1 * ADIM + lane] * (vb1 ? 1.f : 0.f);
            float ba0[16], ba1[16], bb0[16], bb1[16];
            load_bond16(bond, ea0, ba0);
            load_bond16(bond, ea1, ba1);
            load_bond16(bond, eb0, bb0);
            load_bond16(bond, eb1, bb1);

#pragma unroll
            for (int r = 0; r < 16; ++r) {
                ga[r] = fmaf(aa0, ba0[r], ga[r]);
                ga[r] = fmaf(aa1, ba1[r], ga[r]);
                gb[r] = fmaf(ab0, bb0[r], gb[r]);
                gb[r] = fmaf(ab1, bb1[r], gb[r]);
            }
            ga[16] += aa0 + aa1;
            gb[16] += ab0 + ab1;
        }

        // lane j writes G[d, r*64+j]: 128 B contiguous per r (2 lanes/bank)
#pragma unroll
        for (int r = 0; r < 17; ++r) {
            Gs[(2 * w) * GSP + r * 64 + lane]     = f2bf(ga[r]);
            Gs[(2 * w + 1) * GSP + r * 64 + lane] = f2bf(gb[r]);
        }
    }
    __syncthreads();

    // ---- phase B: out = Gs @ K2, K-split x2 across wave pairs -----------
    {
        const int kh   = w >> 2;                   // K-half 0/1
        const int ct   = w & 3;                    // N tile 0..3
        const int m    = lane & 15;
        const int quad = lane >> 4;
        const int c    = ct * 16 + m;              // output col (B col n)
        const unsigned short* Ga = Gs + (size_t)m * GSP;
        const int rlo = kh ? 9 : 0;
        const int rhi = kh ? 17 : 9;               // slice 16 = bias

        f32x4 acc = {0.f, 0.f, 0.f, 0.f};

        const float* ks0 = ((rlo < 16) ? (kern + (size_t)rlo * 4096) : bias)
                           + (size_t)c * 64 + quad * 8;
        float4 x0 = *(const float4*)(ks0);
        float4 x1 = *(const float4*)(ks0 + 4);
        float4 y0 = *(const float4*)(ks0 + 32);
        float4 y1 = *(const float4*)(ks0 + 36);

        for (int r = rlo; r < rhi; ++r) {
            float4 nx0 = {}, nx1 = {}, ny0 = {}, ny1 = {};
            if (r + 1 < rhi) {                     // prefetch next slice
                const float* ns = ((r + 1 < 16) ? (kern + (size_t)(r + 1) * 4096)
                                                : bias)
                                  + (size_t)c * 64 + quad * 8;
                nx0 = *(const float4*)(ns);
                nx1 = *(const float4*)(ns + 4);
                ny0 = *(const float4*)(ns + 32);
                ny1 = *(const float4*)(ns + 36);
            }
            const bf16x8 a0 = *(const bf16x8*)(Ga + r * 64 + quad * 8);
            const bf16x8 a1 = *(const bf16x8*)(Ga + r * 64 + 32 + quad * 8);
            acc = __builtin_amdgcn_mfma_f32_16x16x32_bf16(a0, pack_bf8(x0, x1), acc, 0, 0, 0);
            acc = __builtin_amdgcn_mfma_f32_16x16x32_bf16(a1, pack_bf8(y0, y1), acc, 0, 0, 0);
            x0 = nx0; x1 = nx1; y0 = ny0; y1 = ny1;
        }

        if (kh) pb[ct][lane] = acc;                // upper-half partial
        __syncthreads();
        if (!kh) {
            const f32x4 p = pb[ct][lane];
            acc[0] += p[0]; acc[1] += p[1]; acc[2] += p[2]; acc[3] += p[3];
            // D: row = dlo + quad*4 + rr, col = c. Every out row written once.
#pragma unroll
            for (int rr = 0; rr < 4; ++rr)
                out[(size_t)(dlo + quad * 4 + rr) * ADIM + c] = acc[rr];
        }
    }
}

extern "C" void kernel_launch(void* const* d_in, const int* in_sizes, int n_in,
                              void* d_out, int out_size, void* d_ws, size_t ws_size,
                              hipStream_t stream) {
    const float* atom = (const float*)d_in[0];
    const float* bond = (const float*)d_in[1];
    const int*   pair = (const int*)  d_in[2];
    const float* kern = (const float*)d_in[3];
    const float* bias = (const float*)d_in[4];
    float* out = (float*)d_out;

    int2* eb  = (int2*)d_ws;                         // 2.29 MB buckets
    int*  cnt = (int*)((char*)d_ws + CNT_OFF);       // 17.9 KB counters

    hipMemsetAsync(cnt, 0, NSEG * sizeof(int), stream);
    scatter_kernel<<<NEDGE / 256, 256, 0, stream>>>(pair, cnt, eb);
    fused_kernel<<<NBLK, TPB, 0, stream>>>(atom, bond, cnt, eb, kern, bias, out);
}

// Round 8
// 97.729 us; speedup vs baseline: 2.4604x; 1.1490x over previous
//
#include <hip/hip_runtime.h>

// Problem constants
#define NSEG   4480     // 70 * 64
#define ADIM   64
#define BDIM   16
#define NEDGE  65536
#define DPB    16       // destinations (output rows) per fused block
#define NBLK   (NSEG / DPB)   // 280 blocks
#define TPB    512      // 8 waves: 2 dsts/wave (phase A), K-split GEMM (phase B)
#define CAP    64       // bucket capacity per dst (Poisson mean 14.6, max ~35)
#define GSP    1096     // Gs pitch (bf16 elems): 1088 + 8 pad
#define ALP    68       // atom-stage pitch (f32 elems): 64 + 4 pad

// 3 plain dispatches (R5/R7 structure). R7 measured the failure precisely:
// fused = 43.3 us, VALU 14%, VGPR 48 -- phase A's broadcast-serial edge loop
// was an ~18-step dependent-load chain, sub-serialized 4x by register
// pressure, at only 2.2 waves/SIMD. Fix: lane-parallel gather. Per dst,
// ONE pass covers 16 edges: lane (q,p) loads atom[src_q, p*16..+16) and
// bond[e_q, p*4..+4) -- 5 independent loads/lane, 320 in flight per wave,
// a single latency exposure per ~15-edge dst. Atom tile goes through LDS
// (transpose); bond values are broadcast straight from registers via
// v_readlane with compile-time lane indices (unrolled) -> SGPR FMA operand.
// 280x512 blocks, LDS 74 KB -> 2 blocks/CU (the 280>256 remainder runs
// CONCURRENTLY, no serial tail).
//
// Workspace: eb @ 0 : 4480*64*8 = 2,293,760 B {edge,src} buckets
//            cnt @ 4 MiB : 4480*4 B counters (memset each iteration)
#define CNT_OFF  (4u << 20)

typedef __bf16 bf16x8 __attribute__((ext_vector_type(8)));
typedef float  f32x4  __attribute__((ext_vector_type(4)));

__device__ __forceinline__ unsigned short f2bf(float f) {
    union { float f; unsigned int i; } c; c.f = f;
    unsigned int x = c.i;
    x += 0x7fffu + ((x >> 16) & 1u);   // round-to-nearest-even
    return (unsigned short)(x >> 16);
}

union U8 { unsigned short u[8]; bf16x8 v; };

__device__ __forceinline__ bf16x8 pack_bf8(float4 a, float4 b) {
    U8 r;
    r.u[0] = f2bf(a.x); r.u[1] = f2bf(a.y); r.u[2] = f2bf(a.z); r.u[3] = f2bf(a.w);
    r.u[4] = f2bf(b.x); r.u[5] = f2bf(b.y); r.u[6] = f2bf(b.z); r.u[7] = f2bf(b.w);
    return r.v;
}

// read lane l's copy of v (l compile-time-constant at every call site below)
__device__ __forceinline__ float rl(float v, int l) {
    return __builtin_bit_cast(float,
        __builtin_amdgcn_readlane(__builtin_bit_cast(int, v), l));
}

// ---------------------------------------------------------------------------
// scatter_kernel: edge-parallel bucketing (proven R5/R7). One coalesced int2
// load, one atomicAdd on the 17.9 KB L2-resident counter array, one 8 B
// bucket store. 65536 threads -> latency hidden by TLP.
// ---------------------------------------------------------------------------
__global__ __launch_bounds__(256) void scatter_kernel(
    const int* __restrict__ pair, int* __restrict__ cnt, int2* __restrict__ eb)
{
    const int e  = blockIdx.x * 256 + threadIdx.x;
    const int2 p = ((const int2*)pair)[e];          // .x = dst, .y = src
    const int idx = atomicAdd(&cnt[p.x], 1);
    if (idx < CAP) eb[(size_t)p.x * CAP + idx] = make_int2(e, p.y);
}

// ---------------------------------------------------------------------------
// fused_kernel:
//   phase A (8 waves, 2 dsts each, pass = 16 edges):
//     gather: lane(q=lane>>2, p=lane&3) -> atom[src_q, p*16..+16) (4 float4)
//       + bond[e_q, p*4..+4) (1 float4); invalid slots clamp to bucket slot 0
//       (real finite data, n>=1 inside the loop) and scale atom by 0.
//     stage: atom tile -> LDS Al[w][16][68] f32 (ds_write_b128 x4);
//       s_waitcnt lgkmcnt(0) (DS ops are in-order per wave -> visible).
//     accumulate (fully unrolled): for qq<16: a = Al[qq][lane] (stride-1,
//       conflict-free); b[qq][r] = readlane(bq.{x,y,z,w}, 4*qq+pp) -> SGPR;
//       g[r] = fmaf(s, a, g[r]); g[16] += a (bias slice). 272 wave-FMAs/pass.
//     Exact f32 accum across passes, single bf16 rounding into Gs.
//   phase B (8 waves): out[16,64] = Gs[16,1088] @ K2[1088,64] via
//     mfma_16x16x32_bf16, K-split x2 (kh=w>>2: slices 0..8 / 9..16),
//     software-pipelined B loads straight from kern/bias (8 contiguous
//     floats/lane), partials reduced via LDS. (verbatim from R7, passed)
// Fragment layouts (m89/m91-verified, passed R2-R7): A: row=lane&15,
// k=quad*8+j; B: col=lane&15, k=quad*8+j; D: col=lane&15, row=quad*4+reg.
// LDS: Gs 35,072 + Al 34,816 + pb 4,096 = 73,984 B -> 2 blocks/CU.
// ---------------------------------------------------------------------------
__global__ __launch_bounds__(TPB, 4) void fused_kernel(
    const float* __restrict__ atom,    // [4480, 64]  f32
    const float* __restrict__ bond,    // [65536, 16] f32
    const int*   __restrict__ cnt,     // [4480]
    const int2*  __restrict__ eb,      // [4480, 64] {edge, src}
    const float* __restrict__ kern,    // [16, 4096]  f32
    const float* __restrict__ bias,    // [4096]      f32
    float*       __restrict__ out)     // [4480, 64]  f32
{
    __shared__ unsigned short Gs[DPB * GSP];
    __shared__ float Al[8][16 * ALP];
    __shared__ f32x4 pb[4][64];

    const int t    = threadIdx.x;
    const int lane = t & 63;
    const int w    = t >> 6;                       // wave 0..7
    const int dlo  = blockIdx.x * DPB;
    const int q    = lane >> 2;                    // edge slot within pass
    const int p    = lane & 3;                     // quarter of the rows
    float* myAl = Al[w];

    // ---- phase A: 2 dsts per wave, 16-edge passes -----------------------
#pragma unroll
    for (int half = 0; half < 2; ++half) {
        const int dl = 2 * w + half;
        const int d  = dlo + dl;
        int n = cnt[d]; n = n < CAP ? n : CAP;

        float g[17];
#pragma unroll
        for (int r = 0; r < 17; ++r) g[r] = 0.f;

        for (int kb = 0; kb < n; kb += 16) {
            const int  slot = kb + q;
            const bool val  = slot < n;
            const int2 es   = eb[(size_t)d * CAP + (val ? slot : 0)];
            const float vs  = val ? 1.f : 0.f;

            // gather: 5 independent loads, all in flight together
            const float* ap = atom + (size_t)es.y * ADIM + p * 16;
            float4 a0 = ((const float4*)ap)[0];
            float4 a1 = ((const float4*)ap)[1];
            float4 a2 = ((const float4*)ap)[2];
            float4 a3 = ((const float4*)ap)[3];
            const float4 bq = ((const float4*)(bond + (size_t)es.x * BDIM))[p];

            a0.x *= vs; a0.y *= vs; a0.z *= vs; a0.w *= vs;
            a1.x *= vs; a1.y *= vs; a1.z *= vs; a1.w *= vs;
            a2.x *= vs; a2.y *= vs; a2.z *= vs; a2.w *= vs;
            a3.x *= vs; a3.y *= vs; a3.z *= vs; a3.w *= vs;

            // stage atom tile: A_l[q][p*16..+16)
            float* dst = myAl + q * ALP + p * 16;
            ((float4*)dst)[0] = a0;
            ((float4*)dst)[1] = a1;
            ((float4*)dst)[2] = a2;
            ((float4*)dst)[3] = a3;
            __asm__ __volatile__("s_waitcnt lgkmcnt(0)" ::: "memory");

            // accumulate: g[r] += b[qq][r] * atom[src_qq][lane]
#pragma unroll
            for (int qq = 0; qq < 16; ++qq) {
                const float a = myAl[qq * ALP + lane];
                g[16] += a;                        // bias slice (atom scaled 0 if invalid)
#pragma unroll
                for (int pp = 0; pp < 4; ++pp) {
                    const int sl = 4 * qq + pp;    // compile-time constant
                    g[pp * 4 + 0] = fmaf(rl(bq.x, sl), a, g[pp * 4 + 0]);
                    g[pp * 4 + 1] = fmaf(rl(bq.y, sl), a, g[pp * 4 + 1]);
                    g[pp * 4 + 2] = fmaf(rl(bq.z, sl), a, g[pp * 4 + 2]);
                    g[pp * 4 + 3] = fmaf(rl(bq.w, sl), a, g[pp * 4 + 3]);
                }
            }
        }

        // lane j writes G[d, r*64+j]: stride-1 u16, 2 lanes/bank (free)
#pragma unroll
        for (int r = 0; r < 17; ++r)
            Gs[dl * GSP + r * 64 + lane] = f2bf(g[r]);
    }
    __syncthreads();

    // ---- phase B: out = Gs @ K2, K-split x2 (R7, proven) ----------------
    {
        const int kh   = w >> 2;                   // K-half 0/1
        const int ct   = w & 3;                    // N tile 0..3
        const int m    = lane & 15;
        const int quad = lane >> 4;
        const int c    = ct * 16 + m;              // output col (B col n)
        const unsigned short* Ga = Gs + (size_t)m * GSP;
        const int rlo = kh ? 9 : 0;
        const int rhi = kh ? 17 : 9;               // slice 16 = bias

        f32x4 acc = {0.f, 0.f, 0.f, 0.f};

        const float* ks0 = ((rlo < 16) ? (kern + (size_t)rlo * 4096) : bias)
                           + (size_t)c * 64 + quad * 8;
        float4 x0 = *(const float4*)(ks0);
        float4 x1 = *(const float4*)(ks0 + 4);
        float4 y0 = *(const float4*)(ks0 + 32);
        float4 y1 = *(const float4*)(ks0 + 36);

        for (int r = rlo; r < rhi; ++r) {
            float4 nx0 = {}, nx1 = {}, ny0 = {}, ny1 = {};
            if (r + 1 < rhi) {                     // prefetch next slice
                const float* ns = ((r + 1 < 16) ? (kern + (size_t)(r + 1) * 4096)
                                                : bias)
                                  + (size_t)c * 64 + quad * 8;
                nx0 = *(const float4*)(ns);
                nx1 = *(const float4*)(ns + 4);
                ny0 = *(const float4*)(ns + 32);
                ny1 = *(const float4*)(ns + 36);
            }
            const bf16x8 a0 = *(const bf16x8*)(Ga + r * 64 + quad * 8);
            const bf16x8 a1 = *(const bf16x8*)(Ga + r * 64 + 32 + quad * 8);
            acc = __builtin_amdgcn_mfma_f32_16x16x32_bf16(a0, pack_bf8(x0, x1), acc, 0, 0, 0);
            acc = __builtin_amdgcn_mfma_f32_16x16x32_bf16(a1, pack_bf8(y0, y1), acc, 0, 0, 0);
            x0 = nx0; x1 = nx1; y0 = ny0; y1 = ny1;
        }

        if (kh) pb[ct][lane] = acc;                // upper-half partial
        __syncthreads();
        if (!kh) {
            const f32x4 pr = pb[ct][lane];
            acc[0] += pr[0]; acc[1] += pr[1]; acc[2] += pr[2]; acc[3] += pr[3];
            // D: row = dlo + quad*4 + rr, col = c. Every out row written once.
#pragma unroll
            for (int rr = 0; rr < 4; ++rr)
                out[(size_t)(dlo + quad * 4 + rr) * ADIM + c] = acc[rr];
        }
    }
}

extern "C" void kernel_launch(void* const* d_in, const int* in_sizes, int n_in,
                              void* d_out, int out_size, void* d_ws, size_t ws_size,
                              hipStream_t stream) {
    const float* atom = (const float*)d_in[0];
    const float* bond = (const float*)d_in[1];
    const int*   pair = (const int*)  d_in[2];
    const float* kern = (const float*)d_in[3];
    const float* bias = (const float*)d_in[4];
    float* out = (float*)d_out;

    int2* eb  = (int2*)d_ws;                         // 2.29 MB buckets
    int*  cnt = (int*)((char*)d_ws + CNT_OFF);       // 17.9 KB counters

    hipMemsetAsync(cnt, 0, NSEG * sizeof(int), stream);
    scatter_kernel<<<NEDGE / 256, 256, 0, stream>>>(pair, cnt, eb);
    fused_kernel<<<NBLK, TPB, 0, stream>>>(atom, bond, cnt, eb, kern, bias, out);
}